// Round 1
// baseline (337.419 us; speedup 1.0000x reference)
//
#include <hip/hip_runtime.h>
#include <math.h>

#define DEVFN __device__ __forceinline__

// ---------------------------------------------------------------- helpers
DEVFN float blk_sum(float v, float* s4) {          // 256-thread block sum
  #pragma unroll
  for (int o = 32; o > 0; o >>= 1) v += __shfl_down(v, o, 64);
  __syncthreads();
  if ((threadIdx.x & 63) == 0) s4[threadIdx.x >> 6] = v;
  __syncthreads();
  return s4[0] + s4[1] + s4[2] + s4[3];
}

DEVFN float gelu_f(float x) {
  return 0.5f * x * (1.f + erff(x * 0.7071067811865475f));
}

// ---------------------------------------------------------------- global branch
// block per batch: mean over (C,D,H,W), token embed, LN1
__global__ void k_g_tok(const float* __restrict__ x, const float* __restrict__ tw,
                        const float* __restrict__ tb, const float* __restrict__ g1,
                        const float* __restrict__ b1,
                        float* __restrict__ g_res, float* __restrict__ g_t) {
  __shared__ float s4[4];
  int b = blockIdx.x, tid = threadIdx.x;
  const float* xb = x + b * 55296;
  float acc = 0.f;
  for (int i = tid; i < 55296; i += 256) acc += xb[i];
  float m = blk_sum(acc, s4) * (1.f / 55296.f);
  float tok = m * tw[tid] + tb[tid];
  g_res[b * 256 + tid] = tok;
  float mu = blk_sum(tok, s4) * (1.f / 256.f);
  float d = tok - mu;
  float var = blk_sum(d * d, s4) * (1.f / 256.f);
  g_t[b * 256 + tid] = d * rsqrtf(var + 1e-6f) * g1[tid] + b1[tid];
}

// q/k/v = t @ W ; grid (8, 12) ; col = m*1024 + h*256 + c
__global__ void k_g_qkv(const float* __restrict__ g_t, const float* __restrict__ wq,
                        const float* __restrict__ wk, const float* __restrict__ wv,
                        float* __restrict__ gqkv) {
  __shared__ float ts[256];
  int b = blockIdx.x, tid = threadIdx.x;
  ts[tid] = g_t[b * 256 + tid];
  __syncthreads();
  int col = blockIdx.y * 256 + tid;
  int m = col >> 10, cc = col & 1023;
  const float* W = (m == 0) ? wq : (m == 1) ? wk : wv;
  float acc = 0.f;
  for (int c = 0; c < 256; ++c) acc += ts[c] * W[c * 1024 + cc];
  gqkv[b * 3072 + col] = acc;
}

// rank-1 score attention per (b,h); inorm stats factor through q,k sums
__global__ void k_g_attn(const float* __restrict__ gq, float* __restrict__ g_o) {
  __shared__ float ks[256], vs[256], s4[4];
  int b = blockIdx.x >> 2, h = blockIdx.x & 3;
  int i = threadIdx.x;
  const float* base = gq + b * 3072 + h * 256;
  float q = base[i];
  ks[i] = base[1024 + i];
  vs[i] = base[2048 + i];
  __syncthreads();
  float sum = 0.f, sumsq = 0.f, smax = -1e30f;
  for (int j = 0; j < 256; ++j) {
    float s = q * ks[j];
    sum += s; sumsq += s * s; smax = fmaxf(smax, s);
  }
  float tot  = blk_sum(sum, s4)   * (1.f / 65536.f);
  float tot2 = blk_sum(sumsq, s4) * (1.f / 65536.f);
  float rstd = rsqrtf(tot2 - tot * tot + 1e-5f);
  float den = 0.f, num = 0.f;
  for (int j = 0; j < 256; ++j) {
    float w = expf((q * ks[j] - smax) * rstd);
    den += w; num += w * vs[j];
  }
  g_o[b * 1024 + (i << 2) + h] = num / den;   // (c outer, h inner)
}

// out = o @ wo ; +res ; LN2 ; gelu(mo_w @ t2 + mo_b) -> per-batch vector
__global__ void k_g_out(const float* __restrict__ g_o, const float* __restrict__ wo,
                        const float* __restrict__ g_res, const float* __restrict__ g2,
                        const float* __restrict__ b2, const float* __restrict__ mow,
                        const float* __restrict__ mob, float* __restrict__ g_vec) {
  __shared__ float os[1024], t2s[256], s4[4];
  int b = blockIdx.x, tid = threadIdx.x;
  for (int i = tid; i < 1024; i += 256) os[i] = g_o[b * 1024 + i];
  __syncthreads();
  float acc = 0.f;
  for (int k = 0; k < 1024; ++k) acc += os[k] * wo[k * 256 + tid];
  float val = acc + g_res[b * 256 + tid];
  float mu = blk_sum(val, s4) * (1.f / 256.f);
  float d = val - mu;
  float var = blk_sum(d * d, s4) * (1.f / 256.f);
  float t2 = d * rsqrtf(var + 1e-6f) * g2[tid] + b2[tid];
  t2s[tid] = t2;
  __syncthreads();
  float a2 = mob[tid];
  for (int c = 0; c < 256; ++c) a2 += t2s[c] * mow[tid * 256 + c];
  g_vec[b * 256 + tid] = gelu_f(a2);
}

// ---------------------------------------------------------------- local branch
// patch embed + LN1 ; block per (b,s) token
__global__ void k_l_tok(const float* __restrict__ x, const float* __restrict__ pw,
                        const float* __restrict__ pb, const float* __restrict__ g1,
                        const float* __restrict__ b1,
                        float* __restrict__ res, float* __restrict__ eln) {
  __shared__ float pws[64], s4[4];
  int t = blockIdx.x;
  int b = t / 216, s = t % 216;
  int z = s / 36, y = (s / 6) % 6, xx = s % 6;
  int d = z >> 1, p1 = z & 1, hh = y >> 1, p2 = y & 1, ww = xx >> 1, p3 = xx & 1;
  int p = p1 * 4 + p2 * 2 + p3;
  int c = threadIdx.x;
  if (c < 64) pws[c] = pw[c];
  __syncthreads();
  const float* xb = x + (b * 256 + c) * 216 + (2 * d) * 36 + (2 * hh) * 6 + 2 * ww;
  float v = pb[p];
  #pragma unroll
  for (int q1 = 0; q1 < 2; ++q1)
    #pragma unroll
    for (int q2 = 0; q2 < 2; ++q2)
      #pragma unroll
      for (int q3 = 0; q3 < 2; ++q3)
        v += xb[q1 * 36 + q2 * 6 + q3] * pws[p * 8 + (q1 * 4 + q2 * 2 + q3)];
  res[t * 256 + c] = v;
  float mu = blk_sum(v, s4) * (1.f / 256.f);
  float dd = v - mu;
  float var = blk_sum(dd * dd, s4) * (1.f / 256.f);
  eln[t * 256 + c] = dd * rsqrtf(var + 1e-6f) * g1[c] + b1[c];
}

// concat wq|wk|wv -> (256, 3072)
__global__ void k_wcat(const float* __restrict__ wq, const float* __restrict__ wk,
                       const float* __restrict__ wv, float* __restrict__ Wcat) {
  int idx = blockIdx.x * 256 + threadIdx.x;
  int c = idx / 3072, j = idx % 3072;
  int m = j >> 10, cc = j & 1023;
  const float* W = (m == 0) ? wq : (m == 1) ? wk : wv;
  Wcat[idx] = W[c * 1024 + cc];
}

// generic fp32 GEMM: C[M,N] = A[M,K] @ B[K,N]; 64x64 tile, 4x4 micro, KT=64
__global__ void k_gemm64(const float* __restrict__ A, const float* __restrict__ Bm,
                         float* __restrict__ Cm, int M, int N, int K) {
  __shared__ float a_s[64][65];   // pad 65: 2-way max on scalar reads (free)
  __shared__ float b_s[64][68];   // pad 68: 16B-aligned rows for float4
  int tid = threadIdx.x;
  int tx = tid & 15, ty = tid >> 4;
  int rowblk = blockIdx.x * 64, colblk = blockIdx.y * 64;
  int arr = tid >> 4, akq = tid & 15;      // A staging: row, k-quad
  int bc = tid & 63, bk = tid >> 6;        // B staging: col, k
  float acc[4][4] = {};
  for (int kt = 0; kt < K; kt += 64) {
    #pragma unroll
    for (int i = 0; i < 4; ++i) {
      int r = arr + i * 16;
      const float4 v = *(const float4*)&A[(rowblk + r) * K + kt + akq * 4];
      a_s[r][akq * 4 + 0] = v.x; a_s[r][akq * 4 + 1] = v.y;
      a_s[r][akq * 4 + 2] = v.z; a_s[r][akq * 4 + 3] = v.w;
    }
    #pragma unroll
    for (int i = 0; i < 16; ++i) {
      int kk = bk + i * 4;
      b_s[kk][bc] = Bm[(kt + kk) * N + colblk + bc];
    }
    __syncthreads();
    #pragma unroll 16
    for (int kk = 0; kk < 64; ++kk) {
      float a0 = a_s[ty * 4 + 0][kk], a1 = a_s[ty * 4 + 1][kk];
      float a2 = a_s[ty * 4 + 2][kk], a3 = a_s[ty * 4 + 3][kk];
      float4 b4 = *(const float4*)&b_s[kk][tx * 4];
      acc[0][0] += a0 * b4.x; acc[0][1] += a0 * b4.y; acc[0][2] += a0 * b4.z; acc[0][3] += a0 * b4.w;
      acc[1][0] += a1 * b4.x; acc[1][1] += a1 * b4.y; acc[1][2] += a1 * b4.z; acc[1][3] += a1 * b4.w;
      acc[2][0] += a2 * b4.x; acc[2][1] += a2 * b4.y; acc[2][2] += a2 * b4.z; acc[2][3] += a2 * b4.w;
      acc[3][0] += a3 * b4.x; acc[3][1] += a3 * b4.y; acc[3][2] += a3 * b4.z; acc[3][3] += a3 * b4.w;
    }
    __syncthreads();
  }
  #pragma unroll
  for (int i = 0; i < 4; ++i) {
    float4 o4 = make_float4(acc[i][0], acc[i][1], acc[i][2], acc[i][3]);
    *(float4*)&Cm[(rowblk + ty * 4 + i) * N + colblk + tx * 4] = o4;
  }
}

// local attention per (n=b*27+patch, h): 8-dim inner, inorm+softmax, PV
__global__ void k_l_attn(const float* __restrict__ qkv, float* __restrict__ o_buf) {
  __shared__ float ks[256][12], vs[256][12];   // stride 12: 16B-aligned, conflict-free
  __shared__ float s4[4];
  int n = blockIdx.x, h = blockIdx.y;
  int b = n / 27, patch = n % 27;
  int bz = 2 * (patch / 9), by = 2 * ((patch / 3) % 3), bx = 2 * (patch % 3);
  int i = threadIdx.x;
  int tl[8];
  float q[8];
  #pragma unroll
  for (int p = 0; p < 8; ++p) {
    int sz = bz + (p >> 2), sy = by + ((p >> 1) & 1), sx = bx + (p & 1);
    tl[p] = b * 216 + sz * 36 + sy * 6 + sx;
    const float* row = qkv + tl[p] * 3072 + (i << 2) + h;
    q[p]     = row[0];
    ks[i][p] = row[1024];
    vs[i][p] = row[2048];
  }
  __syncthreads();
  float sum = 0.f, sumsq = 0.f, smax = -1e30f;
  for (int j = 0; j < 256; ++j) {
    float4 k0 = *(const float4*)&ks[j][0], k1 = *(const float4*)&ks[j][4];
    float s = q[0]*k0.x + q[1]*k0.y + q[2]*k0.z + q[3]*k0.w
            + q[4]*k1.x + q[5]*k1.y + q[6]*k1.z + q[7]*k1.w;
    sum += s; sumsq += s * s; smax = fmaxf(smax, s);
  }
  float tot  = blk_sum(sum, s4)   * (1.f / 65536.f);
  float tot2 = blk_sum(sumsq, s4) * (1.f / 65536.f);
  float rstd = rsqrtf(tot2 - tot * tot + 1e-5f);
  float den = 0.f, num[8] = {};
  for (int j = 0; j < 256; ++j) {
    float4 k0 = *(const float4*)&ks[j][0], k1 = *(const float4*)&ks[j][4];
    float s = q[0]*k0.x + q[1]*k0.y + q[2]*k0.z + q[3]*k0.w
            + q[4]*k1.x + q[5]*k1.y + q[6]*k1.z + q[7]*k1.w;
    float w = expf((s - smax) * rstd);
    den += w;
    float4 v0 = *(const float4*)&vs[j][0], v1 = *(const float4*)&vs[j][4];
    num[0] += w * v0.x; num[1] += w * v0.y; num[2] += w * v0.z; num[3] += w * v0.w;
    num[4] += w * v1.x; num[5] += w * v1.y; num[6] += w * v1.z; num[7] += w * v1.w;
  }
  float rden = 1.f / den;
  #pragma unroll
  for (int p = 0; p < 8; ++p)
    o_buf[tl[p] * 1024 + (i << 2) + h] = num[p] * rden;   // (c outer, h inner)
}

// t2 = LN(proj + res) in place over res
__global__ void k_l_ln2(const float* __restrict__ proj, float* __restrict__ res,
                        const float* __restrict__ g2, const float* __restrict__ b2) {
  __shared__ float s4[4];
  int t = blockIdx.x, c = threadIdx.x;
  float v = proj[t * 256 + c] + res[t * 256 + c];
  float mu = blk_sum(v, s4) * (1.f / 256.f);
  float d = v - mu;
  float var = blk_sum(d * d, s4) * (1.f / 256.f);
  res[t * 256 + c] = d * rsqrtf(var + 1e-6f) * g2[c] + b2[c];
}

// mo_w (o,c) -> moT (c,o)
__global__ void k_tr256(const float* __restrict__ A, float* __restrict__ AT) {
  int c = blockIdx.x, o = threadIdx.x;
  AT[c * 256 + o] = A[o * 256 + c];
}

// out = x + g_broadcast + gelu(g3 + mo_b)
__global__ void k_final(const float* __restrict__ x, const float* __restrict__ gvec,
                        const float* __restrict__ g3, const float* __restrict__ mob,
                        float* __restrict__ out) {
  int idx = blockIdx.x * 256 + threadIdx.x;
  int b = idx / 55296;
  int r = idx % 55296;
  int c = r / 216, s = r % 216;
  float lv = gelu_f(g3[(b * 216 + s) * 256 + c] + mob[c]);
  out[idx] = x[idx] + gvec[b * 256 + c] + lv;
}

// ---------------------------------------------------------------- launcher
extern "C" void kernel_launch(void* const* d_in, const int* in_sizes, int n_in,
                              void* d_out, int out_size, void* d_ws, size_t ws_size,
                              hipStream_t stream) {
  const float* x     = (const float*)d_in[0];
  const float* g_tw  = (const float*)d_in[1];
  const float* g_tb  = (const float*)d_in[2];
  const float* g_l1g = (const float*)d_in[3];
  const float* g_l1b = (const float*)d_in[4];
  const float* g_wq  = (const float*)d_in[5];
  const float* g_wk  = (const float*)d_in[6];
  const float* g_wv  = (const float*)d_in[7];
  const float* g_wo  = (const float*)d_in[8];
  const float* g_l2g = (const float*)d_in[9];
  const float* g_l2b = (const float*)d_in[10];
  const float* g_mow = (const float*)d_in[11];
  const float* g_mob = (const float*)d_in[12];
  const float* l_pw  = (const float*)d_in[13];
  const float* l_pb  = (const float*)d_in[14];
  const float* l_l1g = (const float*)d_in[15];
  const float* l_l1b = (const float*)d_in[16];
  const float* l_wq  = (const float*)d_in[17];
  const float* l_wk  = (const float*)d_in[18];
  const float* l_wv  = (const float*)d_in[19];
  const float* l_wo  = (const float*)d_in[20];
  const float* l_l2g = (const float*)d_in[21];
  const float* l_l2b = (const float*)d_in[22];
  const float* l_mow = (const float*)d_in[23];
  const float* l_mob = (const float*)d_in[24];
  float* out = (float*)d_out;
  float* ws  = (float*)d_ws;

  // workspace layout (floats); lifetime-based aliasing noted
  float* g_res = ws + 0;        // 2048
  float* g_t   = ws + 2048;     // 2048
  float* g_qkv = ws + 4096;     // 24576
  float* g_o   = ws + 28672;    // 8192
  float* g_vec = ws + 36864;    // 2048
  float* res   = ws + 40960;    // 442368 ; becomes t2 after k_l_ln2
  float* eln   = ws + 483328;   // 442368 ; dead after qkv gemm -> reused as proj
  float* Wcat  = ws + 925696;   // 786432 ; dead after qkv gemm -> reused as moT
  float* qkv   = ws + 1712128;  // 5308416; dead after l_attn   -> reused as g3
  float* o_buf = ws + 7020544;  // 1769472
  float* proj  = eln;
  float* moT   = Wcat;
  float* g3    = qkv;

  // global branch
  k_g_tok<<<8, 256, 0, stream>>>(x, g_tw, g_tb, g_l1g, g_l1b, g_res, g_t);
  k_g_qkv<<<dim3(8, 12), 256, 0, stream>>>(g_t, g_wq, g_wk, g_wv, g_qkv);
  k_g_attn<<<32, 256, 0, stream>>>(g_qkv, g_o);
  k_g_out<<<8, 256, 0, stream>>>(g_o, g_wo, g_res, g_l2g, g_l2b, g_mow, g_mob, g_vec);

  // local branch
  k_l_tok<<<1728, 256, 0, stream>>>(x, l_pw, l_pb, l_l1g, l_l1b, res, eln);
  k_wcat<<<3072, 256, 0, stream>>>(l_wq, l_wk, l_wv, Wcat);
  k_gemm64<<<dim3(27, 48), 256, 0, stream>>>(eln, Wcat, qkv, 1728, 3072, 256);
  k_l_attn<<<dim3(216, 4), 256, 0, stream>>>(qkv, o_buf);
  k_gemm64<<<dim3(27, 4), 256, 0, stream>>>(o_buf, l_wo, proj, 1728, 256, 1024);
  k_l_ln2<<<1728, 256, 0, stream>>>(proj, res, l_l2g, l_l2b);
  k_tr256<<<256, 256, 0, stream>>>(l_mow, moT);
  k_gemm64<<<dim3(27, 4), 256, 0, stream>>>(res, moT, g3, 1728, 256, 256);
  k_final<<<1728, 256, 0, stream>>>(x, g_vec, g3, l_mob, out);
}

// Round 2
// 289.068 us; speedup vs baseline: 1.1673x; 1.1673x over previous
//
#include <hip/hip_runtime.h>
#include <math.h>

#define DEVFN __device__ __forceinline__

// ---------------------------------------------------------------- helpers
DEVFN float blk_sum(float v, float* s4) {          // 256-thread block sum
  #pragma unroll
  for (int o = 32; o > 0; o >>= 1) v += __shfl_down(v, o, 64);
  __syncthreads();
  if ((threadIdx.x & 63) == 0) s4[threadIdx.x >> 6] = v;
  __syncthreads();
  return s4[0] + s4[1] + s4[2] + s4[3];
}

DEVFN float gelu_f(float x) {
  return 0.5f * x * (1.f + erff(x * 0.7071067811865475f));
}

// ---------------------------------------------------------------- global branch
// block per batch: mean over (C,D,H,W), token embed, LN1
__global__ void k_g_tok(const float* __restrict__ x, const float* __restrict__ tw,
                        const float* __restrict__ tb, const float* __restrict__ g1,
                        const float* __restrict__ b1,
                        float* __restrict__ g_res, float* __restrict__ g_t) {
  __shared__ float s4[4];
  int b = blockIdx.x, tid = threadIdx.x;
  const float* xb = x + b * 55296;
  float acc = 0.f;
  for (int i = tid; i < 55296; i += 256) acc += xb[i];
  float m = blk_sum(acc, s4) * (1.f / 55296.f);
  float tok = m * tw[tid] + tb[tid];
  g_res[b * 256 + tid] = tok;
  float mu = blk_sum(tok, s4) * (1.f / 256.f);
  float d = tok - mu;
  float var = blk_sum(d * d, s4) * (1.f / 256.f);
  g_t[b * 256 + tid] = d * rsqrtf(var + 1e-6f) * g1[tid] + b1[tid];
}

// q/k/v = t @ W ; grid (8, 12) ; col = m*1024 + h*256 + c
__global__ void k_g_qkv(const float* __restrict__ g_t, const float* __restrict__ wq,
                        const float* __restrict__ wk, const float* __restrict__ wv,
                        float* __restrict__ gqkv) {
  __shared__ float ts[256];
  int b = blockIdx.x, tid = threadIdx.x;
  ts[tid] = g_t[b * 256 + tid];
  __syncthreads();
  int col = blockIdx.y * 256 + tid;
  int m = col >> 10, cc = col & 1023;
  const float* W = (m == 0) ? wq : (m == 1) ? wk : wv;
  float acc = 0.f;
  for (int c = 0; c < 256; ++c) acc += ts[c] * W[c * 1024 + cc];
  gqkv[b * 3072 + col] = acc;
}

// rank-1 score attention per (b,h). InstanceNorm stats factor exactly:
// sum_ij q_i k_j = (sum q)(sum k); sum_ij (q_i k_j)^2 = (sum q^2)(sum k^2).
// Row-max skipped: IN-standardized scores are bounded << 88 (fp32 exp range).
__global__ void k_g_attn(const float* __restrict__ gq, float* __restrict__ g_o) {
  __shared__ float ks[256], vs[256], s4[4];
  int b = blockIdx.x >> 2, h = blockIdx.x & 3;
  int i = threadIdx.x;
  const float* base = gq + b * 3072 + h * 256;
  float q = base[i];
  float k = base[1024 + i];
  ks[i] = k;
  vs[i] = base[2048 + i];
  float sq  = blk_sum(q, s4);
  float sq2 = blk_sum(q * q, s4);
  float sk  = blk_sum(k, s4);
  float sk2 = blk_sum(k * k, s4);
  float tot  = sq * sk * (1.f / 65536.f);
  float tot2 = sq2 * sk2 * (1.f / 65536.f);
  float rstd = rsqrtf(tot2 - tot * tot + 1e-5f);
  float A = rstd, B = -tot * rstd;
  float den = 0.f, num = 0.f;
  for (int j = 0; j < 256; ++j) {
    float w = __expf(fmaf(q * ks[j], A, B));
    den += w; num += w * vs[j];
  }
  g_o[b * 1024 + (i << 2) + h] = num / den;   // (c outer, h inner)
}

// out = o @ wo ; +res ; LN2 ; gelu(mo_w @ t2 + mo_b) -> per-batch vector
__global__ void k_g_out(const float* __restrict__ g_o, const float* __restrict__ wo,
                        const float* __restrict__ g_res, const float* __restrict__ g2,
                        const float* __restrict__ b2, const float* __restrict__ mow,
                        const float* __restrict__ mob, float* __restrict__ g_vec) {
  __shared__ float os[1024], t2s[256], s4[4];
  int b = blockIdx.x, tid = threadIdx.x;
  for (int i = tid; i < 1024; i += 256) os[i] = g_o[b * 1024 + i];
  __syncthreads();
  float acc = 0.f;
  for (int k = 0; k < 1024; ++k) acc += os[k] * wo[k * 256 + tid];
  float val = acc + g_res[b * 256 + tid];
  float mu = blk_sum(val, s4) * (1.f / 256.f);
  float d = val - mu;
  float var = blk_sum(d * d, s4) * (1.f / 256.f);
  float t2 = d * rsqrtf(var + 1e-6f) * g2[tid] + b2[tid];
  t2s[tid] = t2;
  __syncthreads();
  float a2 = mob[tid];
  for (int c = 0; c < 256; ++c) a2 += t2s[c] * mow[tid * 256 + c];
  g_vec[b * 256 + tid] = gelu_f(a2);
}

// ---------------------------------------------------------------- local branch
// patch embed + LN1 ; block per (b,s) token
__global__ void k_l_tok(const float* __restrict__ x, const float* __restrict__ pw,
                        const float* __restrict__ pb, const float* __restrict__ g1,
                        const float* __restrict__ b1,
                        float* __restrict__ res, float* __restrict__ eln) {
  __shared__ float pws[64], s4[4];
  int t = blockIdx.x;
  int b = t / 216, s = t % 216;
  int z = s / 36, y = (s / 6) % 6, xx = s % 6;
  int d = z >> 1, p1 = z & 1, hh = y >> 1, p2 = y & 1, ww = xx >> 1, p3 = xx & 1;
  int p = p1 * 4 + p2 * 2 + p3;
  int c = threadIdx.x;
  if (c < 64) pws[c] = pw[c];
  __syncthreads();
  const float* xb = x + (b * 256 + c) * 216 + (2 * d) * 36 + (2 * hh) * 6 + 2 * ww;
  float v = pb[p];
  #pragma unroll
  for (int q1 = 0; q1 < 2; ++q1)
    #pragma unroll
    for (int q2 = 0; q2 < 2; ++q2)
      #pragma unroll
      for (int q3 = 0; q3 < 2; ++q3)
        v += xb[q1 * 36 + q2 * 6 + q3] * pws[p * 8 + (q1 * 4 + q2 * 2 + q3)];
  res[t * 256 + c] = v;
  float mu = blk_sum(v, s4) * (1.f / 256.f);
  float dd = v - mu;
  float var = blk_sum(dd * dd, s4) * (1.f / 256.f);
  eln[t * 256 + c] = dd * rsqrtf(var + 1e-6f) * g1[c] + b1[c];
}

// concat wq|wk|wv -> (256, 3072)
__global__ void k_wcat(const float* __restrict__ wq, const float* __restrict__ wk,
                       const float* __restrict__ wv, float* __restrict__ Wcat) {
  int idx = blockIdx.x * 256 + threadIdx.x;
  int c = idx / 3072, j = idx % 3072;
  int m = j >> 10, cc = j & 1023;
  const float* W = (m == 0) ? wq : (m == 1) ? wk : wv;
  Wcat[idx] = W[c * 1024 + cc];
}

// generic fp32 GEMM: C[M,N] = A[M,K] @ B[K,N]; 64x64 tile, 4x4 micro, KT=64
__global__ void k_gemm64(const float* __restrict__ A, const float* __restrict__ Bm,
                         float* __restrict__ Cm, int M, int N, int K) {
  __shared__ float a_s[64][65];   // pad 65: 2-way max on scalar reads (free)
  __shared__ float b_s[64][68];   // pad 68: 16B-aligned rows for float4
  int tid = threadIdx.x;
  int tx = tid & 15, ty = tid >> 4;
  int rowblk = blockIdx.x * 64, colblk = blockIdx.y * 64;
  int arr = tid >> 4, akq = tid & 15;      // A staging: row, k-quad
  int bc = tid & 63, bk = tid >> 6;        // B staging: col, k
  float acc[4][4] = {};
  for (int kt = 0; kt < K; kt += 64) {
    #pragma unroll
    for (int i = 0; i < 4; ++i) {
      int r = arr + i * 16;
      const float4 v = *(const float4*)&A[(rowblk + r) * K + kt + akq * 4];
      a_s[r][akq * 4 + 0] = v.x; a_s[r][akq * 4 + 1] = v.y;
      a_s[r][akq * 4 + 2] = v.z; a_s[r][akq * 4 + 3] = v.w;
    }
    #pragma unroll
    for (int i = 0; i < 16; ++i) {
      int kk = bk + i * 4;
      b_s[kk][bc] = Bm[(kt + kk) * N + colblk + bc];
    }
    __syncthreads();
    #pragma unroll 16
    for (int kk = 0; kk < 64; ++kk) {
      float a0 = a_s[ty * 4 + 0][kk], a1 = a_s[ty * 4 + 1][kk];
      float a2 = a_s[ty * 4 + 2][kk], a3 = a_s[ty * 4 + 3][kk];
      float4 b4 = *(const float4*)&b_s[kk][tx * 4];
      acc[0][0] += a0 * b4.x; acc[0][1] += a0 * b4.y; acc[0][2] += a0 * b4.z; acc[0][3] += a0 * b4.w;
      acc[1][0] += a1 * b4.x; acc[1][1] += a1 * b4.y; acc[1][2] += a1 * b4.z; acc[1][3] += a1 * b4.w;
      acc[2][0] += a2 * b4.x; acc[2][1] += a2 * b4.y; acc[2][2] += a2 * b4.z; acc[2][3] += a2 * b4.w;
      acc[3][0] += a3 * b4.x; acc[3][1] += a3 * b4.y; acc[3][2] += a3 * b4.z; acc[3][3] += a3 * b4.w;
    }
    __syncthreads();
  }
  #pragma unroll
  for (int i = 0; i < 4; ++i) {
    float4 o4 = make_float4(acc[i][0], acc[i][1], acc[i][2], acc[i][3]);
    *(float4*)&Cm[(rowblk + ty * 4 + i) * N + colblk + tx * 4] = o4;
  }
}

// InstanceNorm stats per (n,h) via Gram factorization:
// sum_ij s = sum_d (sum_c q_cd)(sum_c k_cd); sum_ij s^2 = <Q^TQ, K^TK>.
// Stores A=rstd, B=-mu*rstd for the attention kernel's exp(fma(s,A,B)).
__global__ void k_l_stats(const float* __restrict__ qkv, float* __restrict__ stats) {
  __shared__ float q_s[256][8], k_s[256][8];
  __shared__ float rq[64][4], rk[64][4], rlq[64][4], rlk[64][4];
  int n = blockIdx.x, h = blockIdx.y;
  int b = n / 27, patch = n % 27;
  int bz = 2 * (patch / 9), by = 2 * ((patch / 3) % 3), bx = 2 * (patch % 3);
  int c = threadIdx.x;
  #pragma unroll
  for (int p = 0; p < 8; ++p) {
    int sz = bz + (p >> 2), sy = by + ((p >> 1) & 1), sx = bx + (p & 1);
    const float* row = qkv + (b * 216 + sz * 36 + sy * 6 + sx) * 3072 + (c << 2) + h;
    q_s[c][p] = row[0];
    k_s[c][p] = row[1024];
  }
  __syncthreads();
  int p = c & 63, chunk = c >> 6;
  int d = p >> 3, e = p & 7;
  float aq = 0.f, ak = 0.f, lq = 0.f, lk = 0.f;
  int base = chunk * 64;
  for (int t = 0; t < 64; ++t) {
    int cc = base + t;
    float qd = q_s[cc][d], qe = q_s[cc][e];
    float kd = k_s[cc][d], ke = k_s[cc][e];
    aq += qd * qe; ak += kd * ke;
    if (e == 0) { lq += qd; lk += kd; }
  }
  rq[p][chunk] = aq; rk[p][chunk] = ak; rlq[p][chunk] = lq; rlk[p][chunk] = lk;
  __syncthreads();
  if (c < 64) {
    float gq = rq[c][0] + rq[c][1] + rq[c][2] + rq[c][3];
    float gk = rk[c][0] + rk[c][1] + rk[c][2] + rk[c][3];
    float vprod = gq * gk;
    float vmu = 0.f;
    if ((c & 7) == 0) {
      float slq = rlq[c][0] + rlq[c][1] + rlq[c][2] + rlq[c][3];
      float slk = rlk[c][0] + rlk[c][1] + rlk[c][2] + rlk[c][3];
      vmu = slq * slk;
    }
    #pragma unroll
    for (int o = 32; o > 0; o >>= 1) {
      vprod += __shfl_down(vprod, o, 64);
      vmu   += __shfl_down(vmu, o, 64);
    }
    if (c == 0) {
      float mu = vmu * (1.f / 65536.f);
      float m2 = vprod * (1.f / 65536.f);
      float rstd = rsqrtf(m2 - mu * mu + 1e-5f);
      stats[(((n << 2) + h) << 1) + 0] = rstd;
      stats[(((n << 2) + h) << 1) + 1] = -mu * rstd;
    }
  }
}

// local attention per (n,h): single pass, stats precomputed, row-max skipped
// (IN-standardized scores are bounded far below fp32 exp overflow).
__global__ void k_l_attn(const float* __restrict__ qkv, const float* __restrict__ stats,
                         float* __restrict__ o_buf) {
  __shared__ float ks[256][12], vs[256][12];   // stride 12: 16B-aligned rows
  int n = blockIdx.x, h = blockIdx.y;
  int b = n / 27, patch = n % 27;
  int bz = 2 * (patch / 9), by = 2 * ((patch / 3) % 3), bx = 2 * (patch % 3);
  int i = threadIdx.x;
  int tl[8];
  float q[8];
  #pragma unroll
  for (int p = 0; p < 8; ++p) {
    int sz = bz + (p >> 2), sy = by + ((p >> 1) & 1), sx = bx + (p & 1);
    tl[p] = b * 216 + sz * 36 + sy * 6 + sx;
    const float* row = qkv + tl[p] * 3072 + (i << 2) + h;
    q[p]     = row[0];
    ks[i][p] = row[1024];
    vs[i][p] = row[2048];
  }
  __syncthreads();
  const float2 st = *(const float2*)&stats[((n << 2) + h) << 1];
  float A = st.x, B = st.y;
  float den = 0.f, num[8] = {};
  for (int j = 0; j < 256; ++j) {
    float4 k0 = *(const float4*)&ks[j][0], k1 = *(const float4*)&ks[j][4];
    float s = q[0]*k0.x + q[1]*k0.y + q[2]*k0.z + q[3]*k0.w
            + q[4]*k1.x + q[5]*k1.y + q[6]*k1.z + q[7]*k1.w;
    float w = __expf(fmaf(s, A, B));
    den += w;
    float4 v0 = *(const float4*)&vs[j][0], v1 = *(const float4*)&vs[j][4];
    num[0] += w * v0.x; num[1] += w * v0.y; num[2] += w * v0.z; num[3] += w * v0.w;
    num[4] += w * v1.x; num[5] += w * v1.y; num[6] += w * v1.z; num[7] += w * v1.w;
  }
  float rden = 1.f / den;
  #pragma unroll
  for (int p = 0; p < 8; ++p)
    o_buf[tl[p] * 1024 + (i << 2) + h] = num[p] * rden;   // (c outer, h inner)
}

// t2 = LN(proj + res) in place over res
__global__ void k_l_ln2(const float* __restrict__ proj, float* __restrict__ res,
                        const float* __restrict__ g2, const float* __restrict__ b2) {
  __shared__ float s4[4];
  int t = blockIdx.x, c = threadIdx.x;
  float v = proj[t * 256 + c] + res[t * 256 + c];
  float mu = blk_sum(v, s4) * (1.f / 256.f);
  float d = v - mu;
  float var = blk_sum(d * d, s4) * (1.f / 256.f);
  res[t * 256 + c] = d * rsqrtf(var + 1e-6f) * g2[c] + b2[c];
}

// mo_w (o,c) -> moT (c,o)
__global__ void k_tr256(const float* __restrict__ A, float* __restrict__ AT) {
  int c = blockIdx.x, o = threadIdx.x;
  AT[c * 256 + o] = A[o * 256 + c];
}

// out = x + g_broadcast + gelu(g3 + mo_b)
__global__ void k_final(const float* __restrict__ x, const float* __restrict__ gvec,
                        const float* __restrict__ g3, const float* __restrict__ mob,
                        float* __restrict__ out) {
  int idx = blockIdx.x * 256 + threadIdx.x;
  int b = idx / 55296;
  int r = idx % 55296;
  int c = r / 216, s = r % 216;
  float lv = gelu_f(g3[(b * 216 + s) * 256 + c] + mob[c]);
  out[idx] = x[idx] + gvec[b * 256 + c] + lv;
}

// ---------------------------------------------------------------- launcher
extern "C" void kernel_launch(void* const* d_in, const int* in_sizes, int n_in,
                              void* d_out, int out_size, void* d_ws, size_t ws_size,
                              hipStream_t stream) {
  const float* x     = (const float*)d_in[0];
  const float* g_tw  = (const float*)d_in[1];
  const float* g_tb  = (const float*)d_in[2];
  const float* g_l1g = (const float*)d_in[3];
  const float* g_l1b = (const float*)d_in[4];
  const float* g_wq  = (const float*)d_in[5];
  const float* g_wk  = (const float*)d_in[6];
  const float* g_wv  = (const float*)d_in[7];
  const float* g_wo  = (const float*)d_in[8];
  const float* g_l2g = (const float*)d_in[9];
  const float* g_l2b = (const float*)d_in[10];
  const float* g_mow = (const float*)d_in[11];
  const float* g_mob = (const float*)d_in[12];
  const float* l_pw  = (const float*)d_in[13];
  const float* l_pb  = (const float*)d_in[14];
  const float* l_l1g = (const float*)d_in[15];
  const float* l_l1b = (const float*)d_in[16];
  const float* l_wq  = (const float*)d_in[17];
  const float* l_wk  = (const float*)d_in[18];
  const float* l_wv  = (const float*)d_in[19];
  const float* l_wo  = (const float*)d_in[20];
  const float* l_l2g = (const float*)d_in[21];
  const float* l_l2b = (const float*)d_in[22];
  const float* l_mow = (const float*)d_in[23];
  const float* l_mob = (const float*)d_in[24];
  float* out = (float*)d_out;
  float* ws  = (float*)d_ws;

  // workspace layout (floats); lifetime-based aliasing noted
  float* g_res = ws + 0;        // 2048
  float* g_t   = ws + 2048;     // 2048
  float* g_qkv = ws + 4096;     // 24576
  float* g_o   = ws + 28672;    // 8192
  float* g_vec = ws + 36864;    // 2048
  float* stats = ws + 38912;    // 1728 (864 x {rstd, -mu*rstd})
  float* res   = ws + 40960;    // 442368 ; becomes t2 after k_l_ln2
  float* eln   = ws + 483328;   // 442368 ; dead after qkv gemm -> reused as proj
  float* Wcat  = ws + 925696;   // 786432 ; dead after qkv gemm -> reused as moT
  float* qkv   = ws + 1712128;  // 5308416; dead after l_attn   -> reused as g3
  float* o_buf = ws + 7020544;  // 1769472
  float* proj  = eln;
  float* moT   = Wcat;
  float* g3    = qkv;

  // global branch
  k_g_tok<<<8, 256, 0, stream>>>(x, g_tw, g_tb, g_l1g, g_l1b, g_res, g_t);
  k_g_qkv<<<dim3(8, 12), 256, 0, stream>>>(g_t, g_wq, g_wk, g_wv, g_qkv);
  k_g_attn<<<32, 256, 0, stream>>>(g_qkv, g_o);
  k_g_out<<<8, 256, 0, stream>>>(g_o, g_wo, g_res, g_l2g, g_l2b, g_mow, g_mob, g_vec);

  // local branch
  k_l_tok<<<1728, 256, 0, stream>>>(x, l_pw, l_pb, l_l1g, l_l1b, res, eln);
  k_wcat<<<3072, 256, 0, stream>>>(l_wq, l_wk, l_wv, Wcat);
  k_gemm64<<<dim3(27, 48), 256, 0, stream>>>(eln, Wcat, qkv, 1728, 3072, 256);
  k_l_stats<<<dim3(216, 4), 256, 0, stream>>>(qkv, stats);
  k_l_attn<<<dim3(216, 4), 256, 0, stream>>>(qkv, stats, o_buf);
  k_gemm64<<<dim3(27, 4), 256, 0, stream>>>(o_buf, l_wo, proj, 1728, 256, 1024);
  k_l_ln2<<<1728, 256, 0, stream>>>(proj, res, l_l2g, l_l2b);
  k_tr256<<<256, 256, 0, stream>>>(l_mow, moT);
  k_gemm64<<<dim3(27, 4), 256, 0, stream>>>(res, moT, g3, 1728, 256, 256);
  k_final<<<1728, 256, 0, stream>>>(x, g_vec, g3, l_mob, out);
}

// Round 4
// 242.880 us; speedup vs baseline: 1.3892x; 1.1902x over previous
//
#include <hip/hip_runtime.h>
#include <math.h>

#define DEVFN __device__ __forceinline__

// ---------------------------------------------------------------- helpers
DEVFN float blk_sum(float v, float* s4) {          // 256-thread block sum
  #pragma unroll
  for (int o = 32; o > 0; o >>= 1) v += __shfl_down(v, o, 64);
  __syncthreads();
  if ((threadIdx.x & 63) == 0) s4[threadIdx.x >> 6] = v;
  __syncthreads();
  return s4[0] + s4[1] + s4[2] + s4[3];
}

DEVFN float gelu_f(float x) {
  return 0.5f * x * (1.f + erff(x * 0.7071067811865475f));
}

// ---------------------------------------------------------------- local tok
// patch embed + LN1 ; block per (b,s) token. Also emits per-block partial sum
// of raw x (for the global branch's batch mean) -> g_part[1728], no atomics.
// NOTE: each block sums the FULL 2x2x2 patch, so across the 8 blocks sharing
// a patch every x element is counted 8x -> k_g_tok2 divides by 8*55296.
__global__ void k_l_tok(const float* __restrict__ x, const float* __restrict__ pw,
                        const float* __restrict__ pb, const float* __restrict__ g1,
                        const float* __restrict__ b1,
                        float* __restrict__ res, float* __restrict__ eln,
                        float* __restrict__ g_part) {
  __shared__ float pws[64], s4[4];
  int t = blockIdx.x;
  int b = t / 216, s = t % 216;
  int z = s / 36, y = (s / 6) % 6, xx = s % 6;
  int d = z >> 1, p1 = z & 1, hh = y >> 1, p2 = y & 1, ww = xx >> 1, p3 = xx & 1;
  int p = p1 * 4 + p2 * 2 + p3;
  int c = threadIdx.x;
  if (c < 64) pws[c] = pw[c];
  __syncthreads();
  const float* xb = x + (b * 256 + c) * 216 + (2 * d) * 36 + (2 * hh) * 6 + 2 * ww;
  float v = pb[p];
  float xs = 0.f;
  #pragma unroll
  for (int q1 = 0; q1 < 2; ++q1)
    #pragma unroll
    for (int q2 = 0; q2 < 2; ++q2)
      #pragma unroll
      for (int q3 = 0; q3 < 2; ++q3) {
        float xv = xb[q1 * 36 + q2 * 6 + q3];
        xs += xv;
        v += xv * pws[p * 8 + (q1 * 4 + q2 * 2 + q3)];
      }
  float bs = blk_sum(xs, s4);
  if (c == 0) g_part[t] = bs;
  res[t * 256 + c] = v;
  float mu = blk_sum(v, s4) * (1.f / 256.f);
  float dd = v - mu;
  float var = blk_sum(dd * dd, s4) * (1.f / 256.f);
  eln[t * 256 + c] = dd * rsqrtf(var + 1e-6f) * g1[c] + b1[c];
}

// ---------------------------------------------------------------- global branch
// block per batch: reduce 216 partials (8x over-counted) -> mean, token, LN1
__global__ void k_g_tok2(const float* __restrict__ g_part, const float* __restrict__ tw,
                         const float* __restrict__ tb, const float* __restrict__ g1,
                         const float* __restrict__ b1,
                         float* __restrict__ g_res, float* __restrict__ g_t) {
  __shared__ float s4[4];
  int b = blockIdx.x, tid = threadIdx.x;
  float acc = (tid < 216) ? g_part[b * 216 + tid] : 0.f;
  float m = blk_sum(acc, s4) * (1.f / 442368.f);   // 8 * 55296
  float tok = m * tw[tid] + tb[tid];
  g_res[b * 256 + tid] = tok;
  float mu = blk_sum(tok, s4) * (1.f / 256.f);
  float d = tok - mu;
  float var = blk_sum(d * d, s4) * (1.f / 256.f);
  g_t[b * 256 + tid] = d * rsqrtf(var + 1e-6f) * g1[tid] + b1[tid];
}

// q/k/v = t @ W ; grid (8, 12) ; col = m*1024 + h*256 + c
__global__ void k_g_qkv(const float* __restrict__ g_t, const float* __restrict__ wq,
                        const float* __restrict__ wk, const float* __restrict__ wv,
                        float* __restrict__ gqkv) {
  __shared__ float ts[256];
  int b = blockIdx.x, tid = threadIdx.x;
  ts[tid] = g_t[b * 256 + tid];
  __syncthreads();
  int col = blockIdx.y * 256 + tid;
  int m = col >> 10, cc = col & 1023;
  const float* W = (m == 0) ? wq : (m == 1) ? wk : wv;
  float acc = 0.f;
  for (int c = 0; c < 256; ++c) acc += ts[c] * W[c * 1024 + cc];
  gqkv[b * 3072 + col] = acc;
}

// rank-1 score attention per (b,h). InstanceNorm stats factor exactly:
// sum_ij q_i k_j = (sum q)(sum k); sum_ij (q_i k_j)^2 = (sum q^2)(sum k^2).
// Row-max skipped: IN-standardized scores are bounded << 88 (fp32 exp range).
__global__ void k_g_attn(const float* __restrict__ gq, float* __restrict__ g_o) {
  __shared__ float ks[256], vs[256], s4[4];
  int b = blockIdx.x >> 2, h = blockIdx.x & 3;
  int i = threadIdx.x;
  const float* base = gq + b * 3072 + h * 256;
  float q = base[i];
  float k = base[1024 + i];
  ks[i] = k;
  vs[i] = base[2048 + i];
  float sq  = blk_sum(q, s4);
  float sq2 = blk_sum(q * q, s4);
  float sk  = blk_sum(k, s4);
  float sk2 = blk_sum(k * k, s4);
  float tot  = sq * sk * (1.f / 65536.f);
  float tot2 = sq2 * sk2 * (1.f / 65536.f);
  float rstd = rsqrtf(tot2 - tot * tot + 1e-5f);
  float A = rstd, B = -tot * rstd;
  float den = 0.f, num = 0.f;
  for (int j = 0; j < 256; ++j) {
    float w = __expf(fmaf(q * ks[j], A, B));
    den += w; num += w * vs[j];
  }
  g_o[b * 1024 + (i << 2) + h] = num / den;   // (c outer, h inner)
}

// out = o @ wo ; +res ; LN2 ; gelu(mo_w @ t2 + mo_b) -> per-batch vector
__global__ void k_g_out(const float* __restrict__ g_o, const float* __restrict__ wo,
                        const float* __restrict__ g_res, const float* __restrict__ g2,
                        const float* __restrict__ b2, const float* __restrict__ mow,
                        const float* __restrict__ mob, float* __restrict__ g_vec) {
  __shared__ float os[1024], t2s[256], s4[4];
  int b = blockIdx.x, tid = threadIdx.x;
  for (int i = tid; i < 1024; i += 256) os[i] = g_o[b * 1024 + i];
  __syncthreads();
  float acc = 0.f;
  for (int k = 0; k < 1024; ++k) acc += os[k] * wo[k * 256 + tid];
  float val = acc + g_res[b * 256 + tid];
  float mu = blk_sum(val, s4) * (1.f / 256.f);
  float d = val - mu;
  float var = blk_sum(d * d, s4) * (1.f / 256.f);
  float t2 = d * rsqrtf(var + 1e-6f) * g2[tid] + b2[tid];
  t2s[tid] = t2;
  __syncthreads();
  float a2 = mob[tid];
  for (int c = 0; c < 256; ++c) a2 += t2s[c] * mow[tid * 256 + c];
  g_vec[b * 256 + tid] = gelu_f(a2);
}

// ---------------------------------------------------------------- local branch
// concat wq|wk|wv -> (256, 3072)
__global__ void k_wcat(const float* __restrict__ wq, const float* __restrict__ wk,
                       const float* __restrict__ wv, float* __restrict__ Wcat) {
  int idx = blockIdx.x * 256 + threadIdx.x;
  int c = idx / 3072, j = idx % 3072;
  int m = j >> 10, cc = j & 1023;
  const float* W = (m == 0) ? wq : (m == 1) ? wk : wv;
  Wcat[idx] = W[c * 1024 + cc];
}

// generic fp32 GEMM: C[M,N] = A[M,K] @ B[K,N]; 64x64 tile, 4x4 micro, KT=64
__global__ void k_gemm64(const float* __restrict__ A, const float* __restrict__ Bm,
                         float* __restrict__ Cm, int M, int N, int K) {
  __shared__ float a_s[64][65];   // pad 65: 2-way max on scalar reads (free)
  __shared__ float b_s[64][68];   // pad 68: 16B-aligned rows for float4
  int tid = threadIdx.x;
  int tx = tid & 15, ty = tid >> 4;
  int rowblk = blockIdx.x * 64, colblk = blockIdx.y * 64;
  int arr = tid >> 4, akq = tid & 15;      // A staging: row, k-quad
  int bc = tid & 63, bk = tid >> 6;        // B staging: col, k
  float acc[4][4] = {};
  for (int kt = 0; kt < K; kt += 64) {
    #pragma unroll
    for (int i = 0; i < 4; ++i) {
      int r = arr + i * 16;
      const float4 v = *(const float4*)&A[(rowblk + r) * K + kt + akq * 4];
      a_s[r][akq * 4 + 0] = v.x; a_s[r][akq * 4 + 1] = v.y;
      a_s[r][akq * 4 + 2] = v.z; a_s[r][akq * 4 + 3] = v.w;
    }
    #pragma unroll
    for (int i = 0; i < 16; ++i) {
      int kk = bk + i * 4;
      b_s[kk][bc] = Bm[(kt + kk) * N + colblk + bc];
    }
    __syncthreads();
    #pragma unroll 16
    for (int kk = 0; kk < 64; ++kk) {
      float a0 = a_s[ty * 4 + 0][kk], a1 = a_s[ty * 4 + 1][kk];
      float a2 = a_s[ty * 4 + 2][kk], a3 = a_s[ty * 4 + 3][kk];
      float4 b4 = *(const float4*)&b_s[kk][tx * 4];
      acc[0][0] += a0 * b4.x; acc[0][1] += a0 * b4.y; acc[0][2] += a0 * b4.z; acc[0][3] += a0 * b4.w;
      acc[1][0] += a1 * b4.x; acc[1][1] += a1 * b4.y; acc[1][2] += a1 * b4.z; acc[1][3] += a1 * b4.w;
      acc[2][0] += a2 * b4.x; acc[2][1] += a2 * b4.y; acc[2][2] += a2 * b4.z; acc[2][3] += a2 * b4.w;
      acc[3][0] += a3 * b4.x; acc[3][1] += a3 * b4.y; acc[3][2] += a3 * b4.z; acc[3][3] += a3 * b4.w;
    }
    __syncthreads();
  }
  #pragma unroll
  for (int i = 0; i < 4; ++i) {
    float4 o4 = make_float4(acc[i][0], acc[i][1], acc[i][2], acc[i][3]);
    *(float4*)&Cm[(rowblk + ty * 4 + i) * N + colblk + tx * 4] = o4;
  }
}

// local attention per (n,h): fused InstanceNorm stats (Gram factorization over
// the staged Q/K tiles) + single-pass softmax-PV. Row-max skipped (bounded).
__global__ void k_l_attn(const float* __restrict__ qkv, float* __restrict__ o_buf) {
  __shared__ float ks[256][12], vs[256][12], qs[256][12];  // stride 12: aligned
  __shared__ float rq[64][4], rk[64][4], rlq[64][4], rlk[64][4];
  __shared__ float s_ab[2];
  int n = blockIdx.x, h = blockIdx.y;
  int b = n / 27, patch = n % 27;
  int bz = 2 * (patch / 9), by = 2 * ((patch / 3) % 3), bx = 2 * (patch % 3);
  int i = threadIdx.x;
  int tl[8];
  float q[8];
  #pragma unroll
  for (int p = 0; p < 8; ++p) {
    int sz = bz + (p >> 2), sy = by + ((p >> 1) & 1), sx = bx + (p & 1);
    tl[p] = b * 216 + sz * 36 + sy * 6 + sx;
    const float* row = qkv + tl[p] * 3072 + (i << 2) + h;
    float qv = row[0];
    q[p] = qv;
    qs[i][p] = qv;
    ks[i][p] = row[1024];
    vs[i][p] = row[2048];
  }
  __syncthreads();
  // ---- stats: sum_ij s = sum_d (col-sum q_d)(col-sum k_d);
  //            sum_ij s^2 = <Q^T Q, K^T K>  (8x8 Grams over c)
  {
    int p = i & 63, chunk = i >> 6;
    int d = p >> 3, e = p & 7;
    float aq = 0.f, ak = 0.f, lq = 0.f, lk = 0.f;
    int base = chunk * 64;
    for (int t = 0; t < 64; ++t) {
      int cc = base + t;
      float qd = qs[cc][d], qe = qs[cc][e];
      float kd = ks[cc][d], ke = ks[cc][e];
      aq += qd * qe; ak += kd * ke;
      if (e == 0) { lq += qd; lk += kd; }
    }
    rq[p][chunk] = aq; rk[p][chunk] = ak; rlq[p][chunk] = lq; rlk[p][chunk] = lk;
    __syncthreads();
    if (i < 64) {
      float gq = rq[i][0] + rq[i][1] + rq[i][2] + rq[i][3];
      float gk = rk[i][0] + rk[i][1] + rk[i][2] + rk[i][3];
      float vprod = gq * gk;
      float vmu = 0.f;
      if ((i & 7) == 0) {
        float slq = rlq[i][0] + rlq[i][1] + rlq[i][2] + rlq[i][3];
        float slk = rlk[i][0] + rlk[i][1] + rlk[i][2] + rlk[i][3];
        vmu = slq * slk;
      }
      #pragma unroll
      for (int o = 32; o > 0; o >>= 1) {
        vprod += __shfl_down(vprod, o, 64);
        vmu   += __shfl_down(vmu, o, 64);
      }
      if (i == 0) {
        float mu = vmu * (1.f / 65536.f);
        float m2 = vprod * (1.f / 65536.f);
        float rstd = rsqrtf(m2 - mu * mu + 1e-5f);
        s_ab[0] = rstd;
        s_ab[1] = -mu * rstd;
      }
    }
    __syncthreads();
  }
  float A = s_ab[0], B = s_ab[1];
  float den = 0.f, num[8] = {};
  for (int j = 0; j < 256; ++j) {
    float4 k0 = *(const float4*)&ks[j][0], k1 = *(const float4*)&ks[j][4];
    float s = q[0]*k0.x + q[1]*k0.y + q[2]*k0.z + q[3]*k0.w
            + q[4]*k1.x + q[5]*k1.y + q[6]*k1.z + q[7]*k1.w;
    float w = __expf(fmaf(s, A, B));
    den += w;
    float4 v0 = *(const float4*)&vs[j][0], v1 = *(const float4*)&vs[j][4];
    num[0] += w * v0.x; num[1] += w * v0.y; num[2] += w * v0.z; num[3] += w * v0.w;
    num[4] += w * v1.x; num[5] += w * v1.y; num[6] += w * v1.z; num[7] += w * v1.w;
  }
  float rden = 1.f / den;
  #pragma unroll
  for (int p = 0; p < 8; ++p)
    o_buf[tl[p] * 1024 + (i << 2) + h] = num[p] * rden;   // (c outer, h inner)
}

// t2 = LN(proj + res) in place over res
__global__ void k_l_ln2(const float* __restrict__ proj, float* __restrict__ res,
                        const float* __restrict__ g2, const float* __restrict__ b2) {
  __shared__ float s4[4];
  int t = blockIdx.x, c = threadIdx.x;
  float v = proj[t * 256 + c] + res[t * 256 + c];
  float mu = blk_sum(v, s4) * (1.f / 256.f);
  float d = v - mu;
  float var = blk_sum(d * d, s4) * (1.f / 256.f);
  res[t * 256 + c] = d * rsqrtf(var + 1e-6f) * g2[c] + b2[c];
}

// mo_w (o,c) -> moT (c,o)
__global__ void k_tr256(const float* __restrict__ A, float* __restrict__ AT) {
  int c = blockIdx.x, o = threadIdx.x;
  AT[c * 256 + o] = A[o * 256 + c];
}

// out = x + g_broadcast + gelu(g3 + mo_b)
__global__ void k_final(const float* __restrict__ x, const float* __restrict__ gvec,
                        const float* __restrict__ g3, const float* __restrict__ mob,
                        float* __restrict__ out) {
  int idx = blockIdx.x * 256 + threadIdx.x;
  int b = idx / 55296;
  int r = idx % 55296;
  int c = r / 216, s = r % 216;
  float lv = gelu_f(g3[(b * 216 + s) * 256 + c] + mob[c]);
  out[idx] = x[idx] + gvec[b * 256 + c] + lv;
}

// ---------------------------------------------------------------- launcher
extern "C" void kernel_launch(void* const* d_in, const int* in_sizes, int n_in,
                              void* d_out, int out_size, void* d_ws, size_t ws_size,
                              hipStream_t stream) {
  const float* x     = (const float*)d_in[0];
  const float* g_tw  = (const float*)d_in[1];
  const float* g_tb  = (const float*)d_in[2];
  const float* g_l1g = (const float*)d_in[3];
  const float* g_l1b = (const float*)d_in[4];
  const float* g_wq  = (const float*)d_in[5];
  const float* g_wk  = (const float*)d_in[6];
  const float* g_wv  = (const float*)d_in[7];
  const float* g_wo  = (const float*)d_in[8];
  const float* g_l2g = (const float*)d_in[9];
  const float* g_l2b = (const float*)d_in[10];
  const float* g_mow = (const float*)d_in[11];
  const float* g_mob = (const float*)d_in[12];
  const float* l_pw  = (const float*)d_in[13];
  const float* l_pb  = (const float*)d_in[14];
  const float* l_l1g = (const float*)d_in[15];
  const float* l_l1b = (const float*)d_in[16];
  const float* l_wq  = (const float*)d_in[17];
  const float* l_wk  = (const float*)d_in[18];
  const float* l_wv  = (const float*)d_in[19];
  const float* l_wo  = (const float*)d_in[20];
  const float* l_l2g = (const float*)d_in[21];
  const float* l_l2b = (const float*)d_in[22];
  const float* l_mow = (const float*)d_in[23];
  const float* l_mob = (const float*)d_in[24];
  float* out = (float*)d_out;
  float* ws  = (float*)d_ws;

  // workspace layout (floats); lifetime-based aliasing noted
  float* g_res  = ws + 0;        // 2048
  float* g_t    = ws + 2048;     // 2048
  float* g_qkv  = ws + 4096;     // 24576
  float* g_o    = ws + 28672;    // 8192
  float* g_vec  = ws + 36864;    // 2048
  float* g_part = ws + 38912;    // 1728 (per-block raw-x partial sums, 8x counted)
  float* res    = ws + 40960;    // 442368 ; becomes t2 after k_l_ln2
  float* eln    = ws + 483328;   // 442368 ; dead after qkv gemm -> reused as proj
  float* Wcat   = ws + 925696;   // 786432 ; dead after qkv gemm -> reused as moT
  float* qkv    = ws + 1712128;  // 5308416; dead after l_attn   -> reused as g3
  float* o_buf  = ws + 7020544;  // 1769472
  float* proj   = eln;
  float* moT    = Wcat;
  float* g3     = qkv;

  // local tok first: it feeds both branches (g_part -> global mean)
  k_l_tok<<<1728, 256, 0, stream>>>(x, l_pw, l_pb, l_l1g, l_l1b, res, eln, g_part);
  k_wcat<<<3072, 256, 0, stream>>>(l_wq, l_wk, l_wv, Wcat);

  // global branch
  k_g_tok2<<<8, 256, 0, stream>>>(g_part, g_tw, g_tb, g_l1g, g_l1b, g_res, g_t);
  k_g_qkv<<<dim3(8, 12), 256, 0, stream>>>(g_t, g_wq, g_wk, g_wv, g_qkv);
  k_g_attn<<<32, 256, 0, stream>>>(g_qkv, g_o);
  k_g_out<<<8, 256, 0, stream>>>(g_o, g_wo, g_res, g_l2g, g_l2b, g_mow, g_mob, g_vec);

  // local branch
  k_gemm64<<<dim3(27, 48), 256, 0, stream>>>(eln, Wcat, qkv, 1728, 3072, 256);
  k_l_attn<<<dim3(216, 4), 256, 0, stream>>>(qkv, o_buf);
  k_gemm64<<<dim3(27, 4), 256, 0, stream>>>(o_buf, l_wo, proj, 1728, 256, 1024);
  k_l_ln2<<<1728, 256, 0, stream>>>(proj, res, l_l2g, l_l2b);
  k_tr256<<<256, 256, 0, stream>>>(l_mow, moT);
  k_gemm64<<<dim3(27, 4), 256, 0, stream>>>(res, moT, g3, 1728, 256, 256);
  k_final<<<1728, 256, 0, stream>>>(x, g_vec, g3, l_mob, out);
}

// Round 6
// 187.975 us; speedup vs baseline: 1.7950x; 1.2921x over previous
//
#include <hip/hip_runtime.h>
#include <hip/hip_fp16.h>
#include <stdint.h>
#include <math.h>

#define DEVFN __device__ __forceinline__
typedef unsigned short u16;
typedef short bf16x8 __attribute__((ext_vector_type(8)));
typedef float f32x4  __attribute__((ext_vector_type(4)));
// take the packed-f16 vector type straight from the builtin (gfx950: __fp16 v2)
using h2v = decltype(__builtin_amdgcn_cvt_pkrtz(0.f, 0.f));

// ---------------------------------------------------------------- helpers
DEVFN float blk_sum(float v, float* s4) {          // 256-thread block sum
  #pragma unroll
  for (int o = 32; o > 0; o >>= 1) v += __shfl_down(v, o, 64);
  __syncthreads();
  if ((threadIdx.x & 63) == 0) s4[threadIdx.x >> 6] = v;
  __syncthreads();
  return s4[0] + s4[1] + s4[2] + s4[3];
}

DEVFN float gelu_f(float x) {
  return 0.5f * x * (1.f + erff(x * 0.7071067811865475f));
}

DEVFN u16 bf16_rne(float f) {                      // fp32 -> bf16 round-nearest-even
  uint32_t u = __float_as_uint(f);
  return (u16)((u + 0x7fffu + ((u >> 16) & 1u)) >> 16);
}

DEVFN uint32_t pk_f16(float a, float b) {          // pack 2 fp32 -> f16x2 (RTZ)
  union { h2v h; uint32_t u; } x;
  x.h = __builtin_amdgcn_cvt_pkrtz(a, b);
  return x.u;
}

DEVFN float2 h2f2(uint32_t u) {
  union { uint32_t u; h2v h; } x; x.u = u;
  return make_float2((float)x.h[0], (float)x.h[1]);
}

DEVFN float f16_at(const uint32_t* row, int d) {
  float2 f = h2f2(row[d >> 1]);
  return (d & 1) ? f.y : f.x;
}

#if __has_builtin(__builtin_amdgcn_fdot2)
DEVFN float dot2(uint32_t a, uint32_t b, float c) {
  union { uint32_t u; h2v h; } x, y; x.u = a; y.u = b;
  return __builtin_amdgcn_fdot2(x.h, y.h, c, false);
}
#else
DEVFN float dot2(uint32_t a, uint32_t b, float c) {
  float2 fa = h2f2(a), fb = h2f2(b);
  return fmaf(fa.x, fb.x, fmaf(fa.y, fb.y, c));
}
#endif

// ---------------------------------------------------------------- local tok
// patch embed + LN1 ; block per (b,s) token; eln written as bf16 (GEMM A).
// g_part: raw-x partials, 8x over-counted (full patch read per sub-position).
__global__ void k_l_tok(const float* __restrict__ x, const float* __restrict__ pw,
                        const float* __restrict__ pb, const float* __restrict__ g1,
                        const float* __restrict__ b1,
                        float* __restrict__ res, u16* __restrict__ eln_bf,
                        float* __restrict__ g_part) {
  __shared__ float pws[64], s4[4];
  int t = blockIdx.x;
  int b = t / 216, s = t % 216;
  int z = s / 36, y = (s / 6) % 6, xx = s % 6;
  int d = z >> 1, p1 = z & 1, hh = y >> 1, p2 = y & 1, ww = xx >> 1, p3 = xx & 1;
  int p = p1 * 4 + p2 * 2 + p3;
  int c = threadIdx.x;
  if (c < 64) pws[c] = pw[c];
  __syncthreads();
  const float* xb = x + (b * 256 + c) * 216 + (2 * d) * 36 + (2 * hh) * 6 + 2 * ww;
  float v = pb[p];
  float xs = 0.f;
  #pragma unroll
  for (int q1 = 0; q1 < 2; ++q1)
    #pragma unroll
    for (int q2 = 0; q2 < 2; ++q2)
      #pragma unroll
      for (int q3 = 0; q3 < 2; ++q3) {
        float xv = xb[q1 * 36 + q2 * 6 + q3];
        xs += xv;
        v += xv * pws[p * 8 + (q1 * 4 + q2 * 2 + q3)];
      }
  float bs = blk_sum(xs, s4);
  if (c == 0) g_part[t] = bs;
  res[t * 256 + c] = v;
  float mu = blk_sum(v, s4) * (1.f / 256.f);
  float dd = v - mu;
  float var = blk_sum(dd * dd, s4) * (1.f / 256.f);
  eln_bf[t * 256 + c] = bf16_rne(dd * rsqrtf(var + 1e-6f) * g1[c] + b1[c]);
}

// ---------------------------------------------------------------- global branch
__global__ void k_g_tok2(const float* __restrict__ g_part, const float* __restrict__ tw,
                         const float* __restrict__ tb, const float* __restrict__ g1,
                         const float* __restrict__ b1,
                         float* __restrict__ g_res, float* __restrict__ g_t) {
  __shared__ float s4[4];
  int b = blockIdx.x, tid = threadIdx.x;
  float acc = (tid < 216) ? g_part[b * 216 + tid] : 0.f;
  float m = blk_sum(acc, s4) * (1.f / 442368.f);   // 8 * 55296
  float tok = m * tw[tid] + tb[tid];
  g_res[b * 256 + tid] = tok;
  float mu = blk_sum(tok, s4) * (1.f / 256.f);
  float d = tok - mu;
  float var = blk_sum(d * d, s4) * (1.f / 256.f);
  g_t[b * 256 + tid] = d * rsqrtf(var + 1e-6f) * g1[tid] + b1[tid];
}

__global__ void k_g_qkv(const float* __restrict__ g_t, const float* __restrict__ wq,
                        const float* __restrict__ wk, const float* __restrict__ wv,
                        float* __restrict__ gqkv) {
  __shared__ float ts[256];
  int b = blockIdx.x, tid = threadIdx.x;
  ts[tid] = g_t[b * 256 + tid];
  __syncthreads();
  int col = blockIdx.y * 256 + tid;
  int m = col >> 10, cc = col & 1023;
  const float* W = (m == 0) ? wq : (m == 1) ? wk : wv;
  float acc = 0.f;
  for (int c = 0; c < 256; ++c) acc += ts[c] * W[c * 1024 + cc];
  gqkv[b * 3072 + col] = acc;
}

__global__ void k_g_attn(const float* __restrict__ gq, float* __restrict__ g_o) {
  __shared__ float ks[256], vs[256], s4[4];
  int b = blockIdx.x >> 2, h = blockIdx.x & 3;
  int i = threadIdx.x;
  const float* base = gq + b * 3072 + h * 256;
  float q = base[i];
  float k = base[1024 + i];
  ks[i] = k;
  vs[i] = base[2048 + i];
  float sq  = blk_sum(q, s4);
  float sq2 = blk_sum(q * q, s4);
  float sk  = blk_sum(k, s4);
  float sk2 = blk_sum(k * k, s4);
  float tot  = sq * sk * (1.f / 65536.f);
  float tot2 = sq2 * sk2 * (1.f / 65536.f);
  float rstd = rsqrtf(tot2 - tot * tot + 1e-5f);
  float A = rstd, B = -tot * rstd;
  float den = 0.f, num = 0.f;
  for (int j = 0; j < 256; ++j) {
    float w = __expf(fmaf(q * ks[j], A, B));
    den += w; num += w * vs[j];
  }
  g_o[b * 1024 + (i << 2) + h] = num / den;
}

__global__ void k_g_out(const float* __restrict__ g_o, const float* __restrict__ wo,
                        const float* __restrict__ g_res, const float* __restrict__ g2,
                        const float* __restrict__ b2, const float* __restrict__ mow,
                        const float* __restrict__ mob, float* __restrict__ g_vec) {
  __shared__ float os[1024], t2s[256], s4[4];
  int b = blockIdx.x, tid = threadIdx.x;
  for (int i = tid; i < 1024; i += 256) os[i] = g_o[b * 1024 + i];
  __syncthreads();
  float acc = 0.f;
  for (int k = 0; k < 1024; ++k) acc += os[k] * wo[k * 256 + tid];
  float val = acc + g_res[b * 256 + tid];
  float mu = blk_sum(val, s4) * (1.f / 256.f);
  float d = val - mu;
  float var = blk_sum(d * d, s4) * (1.f / 256.f);
  float t2 = d * rsqrtf(var + 1e-6f) * g2[tid] + b2[tid];
  t2s[tid] = t2;
  __syncthreads();
  float a2 = mob[tid];
  for (int c = 0; c < 256; ++c) a2 += t2s[c] * mow[tid * 256 + c];
  g_vec[b * 256 + tid] = gelu_f(a2);
}

// ---------------------------------------------------------------- weight prep
// tiled transpose + cast: in fp32 [R][C] -> out bf16 [C][R]
__global__ void k_trc(const float* __restrict__ in, u16* __restrict__ out,
                      int R, int C) {
  __shared__ float tile[32][33];
  int r0 = blockIdx.x * 32, c0 = blockIdx.y * 32;
  int tx = threadIdx.x & 31, ty = threadIdx.x >> 5;
  for (int i = ty; i < 32; i += 8) tile[i][tx] = in[(r0 + i) * C + c0 + tx];
  __syncthreads();
  for (int i = ty; i < 32; i += 8)
    out[(size_t)(c0 + i) * R + r0 + tx] = bf16_rne(tile[tx][i]);
}

__global__ void k_cast(const float* __restrict__ in, u16* __restrict__ out, int n) {
  int i = blockIdx.x * 256 + threadIdx.x;
  if (i < n) out[i] = bf16_rne(in[i]);
}

// ---------------------------------------------------------------- bf16 MFMA GEMM
// C[M][N] fp32 = A[M][K] bf16 @ BT[N][K] bf16  (B stored N-major = B^T)
// 64x64 tile, BK=32, 4 waves (2x2), 16x16x32 MFMA, 2x2 frags per wave.
__global__ __launch_bounds__(256) void k_gemm_bf16(
    const u16* __restrict__ A, const u16* __restrict__ BT,
    float* __restrict__ C, int M, int N, int K) {
  __shared__ __align__(16) u16 a_s[64][40];   // pad 40: 80B rows, 2-way max
  __shared__ __align__(16) u16 b_s[64][40];
  int tid = threadIdx.x;
  int rowblk = blockIdx.x * 64, colblk = blockIdx.y * 64;
  int sr = tid & 63, sk = (tid >> 6) * 8;     // staging: row, k-chunk
  int lane = tid & 63, w = tid >> 6;
  int wr = (w >> 1) * 32, wc = (w & 1) * 32;  // wave's 32x32 quadrant
  int fm = lane & 15, fk = (lane >> 4) * 8;   // frag: m/n idx, k-chunk
  f32x4 acc[2][2] = {};
  for (int kt = 0; kt < K; kt += 32) {
    __syncthreads();
    *(uint4*)&a_s[sr][sk] = *(const uint4*)&A[(size_t)(rowblk + sr) * K + kt + sk];
    *(uint4*)&b_s[sr][sk] = *(const uint4*)&BT[(size_t)(colblk + sr) * K + kt + sk];
    __syncthreads();
    bf16x8 bn[2];
    #pragma unroll
    for (int ni = 0; ni < 2; ++ni) bn[ni] = *(const bf16x8*)&b_s[wc + ni * 16 + fm][fk];
    #pragma unroll
    for (int mi = 0; mi < 2; ++mi) {
      bf16x8 af = *(const bf16x8*)&a_s[wr + mi * 16 + fm][fk];
      #pragma unroll
      for (int ni = 0; ni < 2; ++ni)
        acc[mi][ni] = __builtin_amdgcn_mfma_f32_16x16x32_bf16(af, bn[ni], acc[mi][ni], 0, 0, 0);
    }
  }
  int crow0 = rowblk + wr + (lane >> 4) * 4;
  int ccol  = colblk + wc + fm;
  #pragma unroll
  for (int mi = 0; mi < 2; ++mi)
    #pragma unroll
    for (int ni = 0; ni < 2; ++ni)
      #pragma unroll
      for (int r = 0; r < 4; ++r)
        C[(size_t)(crow0 + mi * 16 + r) * N + ccol + ni * 16] = acc[mi][ni][r];
}

// ---------------------------------------------------------------- local attention
// block = (n,h), 128 threads, 2 q-rows/thread. Q/K/V staged as packed f16
// (16B/row): j-loop does 2 LDS b128 reads serving 2 rows. Stats via Gram
// factorization on the same f16-rounded values. Output bf16 (GEMM A).
__global__ __launch_bounds__(128) void k_l_attn(const float* __restrict__ qkv,
                                                u16* __restrict__ o_buf) {
  __shared__ uint4 qL[256], kL[256], vL[256];
  __shared__ float rq[64][2], rk[64][2], rlq[64][2], rlk[64][2], s_ab[2];
  int n = blockIdx.x, h = blockIdx.y;
  int b = n / 27, patch = n % 27;
  int bz = 2 * (patch / 9), by = 2 * ((patch / 3) % 3), bx = 2 * (patch % 3);
  int t = threadIdx.x;
  int tl[8];
  #pragma unroll
  for (int p = 0; p < 8; ++p) {
    int sz = bz + (p >> 2), sy = by + ((p >> 1) & 1), sx = bx + (p & 1);
    tl[p] = b * 216 + sz * 36 + sy * 6 + sx;
  }
  #pragma unroll
  for (int rr = 0; rr < 2; ++rr) {
    int c = t + rr * 128;
    float qv[8], kv[8], vv[8];
    #pragma unroll
    for (int p = 0; p < 8; ++p) {
      const float* row = qkv + (size_t)tl[p] * 3072 + (c << 2) + h;
      qv[p] = row[0]; kv[p] = row[1024]; vv[p] = row[2048];
    }
    qL[c] = make_uint4(pk_f16(qv[0], qv[1]), pk_f16(qv[2], qv[3]),
                       pk_f16(qv[4], qv[5]), pk_f16(qv[6], qv[7]));
    kL[c] = make_uint4(pk_f16(kv[0], kv[1]), pk_f16(kv[2], kv[3]),
                       pk_f16(kv[4], kv[5]), pk_f16(kv[6], kv[7]));
    vL[c] = make_uint4(pk_f16(vv[0], vv[1]), pk_f16(vv[2], vv[3]),
                       pk_f16(vv[4], vv[5]), pk_f16(vv[6], vv[7]));
  }
  __syncthreads();
  // ---- InstanceNorm stats: sum_ij s = sum_d (colsum q_d)(colsum k_d);
  //      sum_ij s^2 = <Q^TQ, K^TK> (8x8 Grams over c), on f16-rounded Q,K.
  {
    int p = t & 63, chunk = t >> 6;
    int d = p >> 3, e = p & 7;
    float aq = 0.f, ak = 0.f, lq = 0.f, lk = 0.f;
    for (int cc = chunk * 128; cc < chunk * 128 + 128; ++cc) {
      const uint32_t* qr = (const uint32_t*)&qL[cc];
      const uint32_t* kr = (const uint32_t*)&kL[cc];
      float qd = f16_at(qr, d), qe = f16_at(qr, e);
      float kd = f16_at(kr, d), ke = f16_at(kr, e);
      aq += qd * qe; ak += kd * ke;
      if (e == 0) { lq += qd; lk += kd; }
    }
    rq[p][chunk] = aq; rk[p][chunk] = ak; rlq[p][chunk] = lq; rlk[p][chunk] = lk;
    __syncthreads();
    if (t < 64) {
      float gq = rq[t][0] + rq[t][1];
      float gk = rk[t][0] + rk[t][1];
      float vprod = gq * gk;
      float vmu = 0.f;
      if ((t & 7) == 0) {
        float slq = rlq[t][0] + rlq[t][1];
        float slk = rlk[t][0] + rlk[t][1];
        vmu = slq * slk;
      }
      #pragma unroll
      for (int o = 32; o > 0; o >>= 1) {
        vprod += __shfl_down(vprod, o, 64);
        vmu   += __shfl_down(vmu, o, 64);
      }
      if (t == 0) {
        float mu = vmu * (1.f / 65536.f);
        float m2 = vprod * (1.f / 65536.f);
        float rstd = rsqrtf(m2 - mu * mu + 1e-5f);
        s_ab[0] = rstd;
        s_ab[1] = -mu * rstd;
      }
    }
    __syncthreads();
  }
  float A = s_ab[0], B = s_ab[1];
  uint4 qa = qL[t], qb = qL[t + 128];
  float dena = 0.f, denb = 0.f, numa[8] = {}, numb[8] = {};
  for (int j = 0; j < 256; ++j) {
    uint4 kw = kL[j];
    float sa = dot2(kw.w, qa.w, dot2(kw.z, qa.z, dot2(kw.y, qa.y, dot2(kw.x, qa.x, 0.f))));
    float sb = dot2(kw.w, qb.w, dot2(kw.z, qb.z, dot2(kw.y, qb.y, dot2(kw.x, qb.x, 0.f))));
    float wa = __expf(fmaf(sa, A, B));
    float wb = __expf(fmaf(sb, A, B));
    dena += wa; denb += wb;
    uint4 vw = vL[j];
    float2 v0 = h2f2(vw.x), v1 = h2f2(vw.y), v2 = h2f2(vw.z), v3 = h2f2(vw.w);
    numa[0] += wa * v0.x; numa[1] += wa * v0.y; numa[2] += wa * v1.x; numa[3] += wa * v1.y;
    numa[4] += wa * v2.x; numa[5] += wa * v2.y; numa[6] += wa * v3.x; numa[7] += wa * v3.y;
    numb[0] += wb * v0.x; numb[1] += wb * v0.y; numb[2] += wb * v1.x; numb[3] += wb * v1.y;
    numb[4] += wb * v2.x; numb[5] += wb * v2.y; numb[6] += wb * v3.x; numb[7] += wb * v3.y;
  }
  float ra = 1.f / dena, rb = 1.f / denb;
  #pragma unroll
  for (int p = 0; p < 8; ++p) {
    o_buf[(size_t)tl[p] * 1024 + (t << 2) + h]         = bf16_rne(numa[p] * ra);
    o_buf[(size_t)tl[p] * 1024 + ((t + 128) << 2) + h] = bf16_rne(numb[p] * rb);
  }
}

// t2 = LN(proj + res) -> bf16 (mo-GEMM A)
__global__ void k_l_ln2(const float* __restrict__ proj, const float* __restrict__ res,
                        const float* __restrict__ g2, const float* __restrict__ b2,
                        u16* __restrict__ t2b) {
  __shared__ float s4[4];
  int t = blockIdx.x, c = threadIdx.x;
  float v = proj[t * 256 + c] + res[t * 256 + c];
  float mu = blk_sum(v, s4) * (1.f / 256.f);
  float d = v - mu;
  float var = blk_sum(d * d, s4) * (1.f / 256.f);
  t2b[t * 256 + c] = bf16_rne(d * rsqrtf(var + 1e-6f) * g2[c] + b2[c]);
}

// out = x + g_broadcast + gelu(g3 + mo_b)
__global__ void k_final(const float* __restrict__ x, const float* __restrict__ gvec,
                        const float* __restrict__ g3, const float* __restrict__ mob,
                        float* __restrict__ out) {
  int idx = blockIdx.x * 256 + threadIdx.x;
  int b = idx / 55296;
  int r = idx % 55296;
  int c = r / 216, s = r % 216;
  float lv = gelu_f(g3[(b * 216 + s) * 256 + c] + mob[c]);
  out[idx] = x[idx] + gvec[b * 256 + c] + lv;
}

// ---------------------------------------------------------------- launcher
extern "C" void kernel_launch(void* const* d_in, const int* in_sizes, int n_in,
                              void* d_out, int out_size, void* d_ws, size_t ws_size,
                              hipStream_t stream) {
  const float* x     = (const float*)d_in[0];
  const float* g_tw  = (const float*)d_in[1];
  const float* g_tb  = (const float*)d_in[2];
  const float* g_l1g = (const float*)d_in[3];
  const float* g_l1b = (const float*)d_in[4];
  const float* g_wq  = (const float*)d_in[5];
  const float* g_wk  = (const float*)d_in[6];
  const float* g_wv  = (const float*)d_in[7];
  const float* g_wo  = (const float*)d_in[8];
  const float* g_l2g = (const float*)d_in[9];
  const float* g_l2b = (const float*)d_in[10];
  const float* g_mow = (const float*)d_in[11];
  const float* g_mob = (const float*)d_in[12];
  const float* l_pw  = (const float*)d_in[13];
  const float* l_pb  = (const float*)d_in[14];
  const float* l_l1g = (const float*)d_in[15];
  const float* l_l1b = (const float*)d_in[16];
  const float* l_wq  = (const float*)d_in[17];
  const float* l_wk  = (const float*)d_in[18];
  const float* l_wv  = (const float*)d_in[19];
  const float* l_wo  = (const float*)d_in[20];
  const float* l_l2g = (const float*)d_in[21];
  const float* l_l2b = (const float*)d_in[22];
  const float* l_mow = (const float*)d_in[23];
  const float* l_mob = (const float*)d_in[24];
  float* out = (float*)d_out;
  float* ws  = (float*)d_ws;

  // workspace layout (float offsets; bf16 regions hold 2 vals per float slot)
  float* g_res  = ws + 0;        // 2048
  float* g_t    = ws + 2048;     // 2048
  float* g_qkv  = ws + 4096;     // 24576
  float* g_o    = ws + 28672;    // 8192
  float* g_vec  = ws + 36864;    // 2048
  float* g_part = ws + 38912;    // 1728
  float* res    = ws + 40960;    // 442368 f32
  u16*   eln_bf = (u16*)(ws + 483328);   // 442368 u16
  u16*   WcatT  = (u16*)(ws + 704512);   // 786432 u16 [3072][256]->[j][c]
  u16*   woT    = (u16*)(ws + 1097728);  // 262144 u16 [256][1024]
  u16*   moB    = (u16*)(ws + 1228800);  // 65536  u16 (mo_w as-is: [o][c]=BT)
  float* qkv    = ws + 1261568;  // 5308416 f32 ; dead after attn -> g3
  u16*   o_buf  = (u16*)(ws + 6569984);  // 1769472 u16
  float* proj   = ws + 7454720;  // 442368 f32
  u16*   t2b    = (u16*)(ws + 7897088);  // 442368 u16
  float* g3     = qkv;

  // weight prep (independent)
  k_trc<<<dim3(8, 32), 256, 0, stream>>>(l_wq, WcatT,          256, 1024);
  k_trc<<<dim3(8, 32), 256, 0, stream>>>(l_wk, WcatT + 262144, 256, 1024);
  k_trc<<<dim3(8, 32), 256, 0, stream>>>(l_wv, WcatT + 524288, 256, 1024);
  k_trc<<<dim3(32, 8), 256, 0, stream>>>(l_wo, woT, 1024, 256);
  k_cast<<<256, 256, 0, stream>>>(l_mow, moB, 65536);

  // local tok (feeds both branches)
  k_l_tok<<<1728, 256, 0, stream>>>(x, l_pw, l_pb, l_l1g, l_l1b, res, eln_bf, g_part);

  // global branch (fp32 throughout)
  k_g_tok2<<<8, 256, 0, stream>>>(g_part, g_tw, g_tb, g_l1g, g_l1b, g_res, g_t);
  k_g_qkv<<<dim3(8, 12), 256, 0, stream>>>(g_t, g_wq, g_wk, g_wv, g_qkv);
  k_g_attn<<<32, 256, 0, stream>>>(g_qkv, g_o);
  k_g_out<<<8, 256, 0, stream>>>(g_o, g_wo, g_res, g_l2g, g_l2b, g_mow, g_mob, g_vec);

  // local branch (bf16 MFMA GEMMs + f16 attention)
  k_gemm_bf16<<<dim3(27, 48), 256, 0, stream>>>(eln_bf, WcatT, qkv, 1728, 3072, 256);
  k_l_attn<<<dim3(216, 4), 128, 0, stream>>>(qkv, o_buf);
  k_gemm_bf16<<<dim3(27, 4), 256, 0, stream>>>(o_buf, woT, proj, 1728, 256, 1024);
  k_l_ln2<<<1728, 256, 0, stream>>>(proj, res, l_l2g, l_l2b, t2b);
  k_gemm_bf16<<<dim3(27, 4), 256, 0, stream>>>(t2b, moB, g3, 1728, 256, 256);
  k_final<<<1728, 256, 0, stream>>>(x, g_vec, g3, l_mob, out);
}